// Round 10
// baseline (106.176 us; speedup 1.0000x reference)
//
#include <hip/hip_runtime.h>

// FieldWeightedFactorizationMachine forward — round 9: sc0 sc1 (bypass L1+L2,
// ALLOW MALL allocation) on the embedding gathers.
// B=32768 rows; F=39 fields; D=64 dims; V=1e6 vocab.
// Rationale: 44% of gathers are within-batch repeats and the 185MB unique row
// set fits the 256MB Infinity Cache, but round-3's `nt` flag is the MALL
// no-allocate hint — it threw that reuse away. gfx950 policy bits:
// sc0=bypass L1, sc1=bypass L2, nt=no-allocate MALL. We want bypass-L2 (keep
// bias table resident there) + temporal in MALL.

#define FW_B 32768
#define FW_F 39
#define FW_D 64

// saddr-form load, bypass L1+L2, allocate in MALL. byte_off is a 32-bit
// byte offset (max 1e6*256 = 2.56e8 < 2^32).
__device__ __forceinline__ float ld_mall(const float* base, unsigned byte_off) {
    float r;
    asm volatile("global_load_dword %0, %1, %2 sc0 sc1"
                 : "=v"(r)
                 : "v"(byte_off), "s"(base));
    return r;
}

__global__ __launch_bounds__(256, 4) void fwfm_kernel(
    const int*   __restrict__ x,      // (B, F)
    const float* __restrict__ emb,    // (V, D)
    const float* __restrict__ bias,   // (V, 1)
    const float* __restrict__ W,      // (F, F)
    const float* __restrict__ w0,     // (1,)
    float*       __restrict__ out)    // (B,)
{
    const int wave = threadIdx.x >> 6;            // 0..3
    const int lane = threadIdx.x & 63;            // dim d
    const int row  = blockIdx.x * 4 + wave;
    if (row >= FW_B) return;

    // Per-lane bias contribution: lane i (i<39) gathers bias[idx_i].
    // Temporal load — we WANT the 4MB bias table L2-resident.
    float part = 0.0f;
    if (lane < FW_F) {
        const int idxl = x[row * FW_F + lane];
        part = bias[(unsigned)idxl];
    }

    // Gather embeddings: uniform idx load, then sc0 sc1 load (skip L1/L2,
    // allocate in Infinity Cache). All 39 issue back-to-back; one drain.
    float v[FW_F];
    #pragma unroll
    for (int i = 0; i < FW_F; ++i) {
        const int si = x[row * FW_F + i];                   // wave-uniform
        const unsigned boff =
            ((unsigned)si * (unsigned)FW_D + (unsigned)lane) * 4u;
        v[i] = ld_mall(emb, boff);
    }
    asm volatile("s_waitcnt vmcnt(0)" ::: "memory");
    __builtin_amdgcn_sched_barrier(0);   // rule #18: fence reg-only reordering

    // Upper-triangular weighted pairwise products for this lane's dim.
    // W reads are wave-uniform with compile-time offsets -> scalar loads.
    #pragma unroll
    for (int i = 0; i < FW_F - 1; ++i) {
        float s = 0.0f;
        #pragma unroll
        for (int j = i + 1; j < FW_F; ++j)
            s = fmaf(W[i * FW_F + j], v[j], s);
        part = fmaf(v[i], s, part);
    }

    // Reduce (interactions + bias) over the 64 lanes.
    #pragma unroll
    for (int off = 32; off >= 1; off >>= 1)
        part += __shfl_xor(part, off, 64);

    if (lane == 0)
        out[row] = w0[0] + part;
}

extern "C" void kernel_launch(void* const* d_in, const int* in_sizes, int n_in,
                              void* d_out, int out_size, void* d_ws, size_t ws_size,
                              hipStream_t stream) {
    const int*   x    = (const int*)  d_in[0];
    const float* emb  = (const float*)d_in[1];
    const float* bias = (const float*)d_in[2];
    const float* W    = (const float*)d_in[3];
    const float* w0   = (const float*)d_in[4];
    float* out        = (float*)d_out;

    const int rows_per_block = 4;                  // 4 waves x 64 lanes
    const int grid = (FW_B + rows_per_block - 1) / rows_per_block;
    fwfm_kernel<<<grid, 256, 0, stream>>>(x, emb, bias, W, w0, out);
}

// Round 11
// 71.535 us; speedup vs baseline: 1.4842x; 1.4842x over previous
//
#include <hip/hip_runtime.h>

// FieldWeightedFactorizationMachine forward — round 10: 2 rows/wave, packed f32.
// B=32768 rows; F=39 fields; D=64 dims; V=1e6 vocab.
// h=lane>>5 selects the half-wave's row; l=lane&31 owns dims {2l,2l+1} (float2).
// - 39 NT gather instructions load TWO rows (19.5 vmem/row vs 39).
// - Interaction triangle runs on float2 -> v_pk_fma_f32 (VALU issue/row halved).
// - Same bytes, same coalescing (each 32-lane half reads a 256B row segment),
//   same nt cache policy as the 73.7us best.

#define FW_B 32768
#define FW_F 39
#define FW_D 64

typedef float f2 __attribute__((ext_vector_type(2)));

__global__ __launch_bounds__(256, 4) void fwfm_kernel(
    const int*   __restrict__ x,      // (B, F)
    const float* __restrict__ emb,    // (V, D)
    const float* __restrict__ bias,   // (V, 1)
    const float* __restrict__ W,      // (F, F)
    const float* __restrict__ w0,     // (1,)
    float*       __restrict__ out)    // (B,)
{
    const int wave = threadIdx.x >> 6;            // 0..3
    const int lane = threadIdx.x & 63;
    const int h    = lane >> 5;                   // which row of the pair
    const int l    = lane & 31;                   // dim-pair: dims 2l, 2l+1
    const int wid  = blockIdx.x * 4 + wave;
    const int row  = wid * 2 + h;                 // grid sized exactly: row < B

    // Fields 0..31 of this half's row (lane l -> field l):
    const int ia = x[row * FW_F + l];
    // Fields 32..38 at lanes l<7 (clamped elsewhere; only lanes 0..6 are used):
    const int ib = x[row * FW_F + 32 + (l < 7 ? l : 6)];

    // Bias sum for this row, spread over the half-wave's lanes.
    float bsum = bias[(unsigned)ia];
    if (l < 7) bsum += bias[(unsigned)ib];

    // Gather: 39 NT float2 loads serve BOTH rows (half-waves use their own idx).
    // __shfl with per-lane source (h-dependent) -> ds_bpermute.
    f2 v[FW_F];
    const int src = lane & 32;                    // base lane of this half
    #pragma unroll
    for (int i = 0; i < 32; ++i) {
        const int si = __shfl(ia, src + i, 64);
        const unsigned off = (unsigned)si * (unsigned)FW_D + 2u * (unsigned)l;
        v[i] = __builtin_nontemporal_load(reinterpret_cast<const f2*>(emb + off));
    }
    #pragma unroll
    for (int i = 32; i < FW_F; ++i) {
        const int si = __shfl(ib, src + (i - 32), 64);
        const unsigned off = (unsigned)si * (unsigned)FW_D + 2u * (unsigned)l;
        v[i] = __builtin_nontemporal_load(reinterpret_cast<const f2*>(emb + off));
    }

    // Upper-triangular weighted pairwise products, packed 2 dims/lane.
    // W reads wave-uniform, compile-time offsets -> scalar loads; splat to f2.
    f2 acc = {0.0f, 0.0f};
    #pragma unroll
    for (int i = 0; i < FW_F - 1; ++i) {
        f2 s = {0.0f, 0.0f};
        #pragma unroll
        for (int j = i + 1; j < FW_F; ++j) {
            const float wv = W[i * FW_F + j];
            s += wv * v[j];                       // v_pk_fma_f32
        }
        acc += v[i] * s;                          // v_pk_fma_f32
    }

    // Per-lane total (2 dims + bias share), then reduce over the 32-lane half.
    float t = acc.x + acc.y + bsum;
    #pragma unroll
    for (int off = 16; off >= 1; off >>= 1)
        t += __shfl_xor(t, off, 64);              // xor<32: stays within half

    if (l == 0)
        out[row] = w0[0] + t;
}

extern "C" void kernel_launch(void* const* d_in, const int* in_sizes, int n_in,
                              void* d_out, int out_size, void* d_ws, size_t ws_size,
                              hipStream_t stream) {
    const int*   x    = (const int*)  d_in[0];
    const float* emb  = (const float*)d_in[1];
    const float* bias = (const float*)d_in[2];
    const float* W    = (const float*)d_in[3];
    const float* w0   = (const float*)d_in[4];
    float* out        = (float*)d_out;

    const int rows_per_block = 4 * 2;              // 4 waves x 2 rows
    const int grid = FW_B / rows_per_block;        // 4096, exact
    fwfm_kernel<<<grid, 256, 0, stream>>>(x, emb, bias, W, w0, out);
}